// Round 1
// 9239.640 us; speedup vs baseline: 1.2791x; 1.2791x over previous
//
#include <hip/hip_runtime.h>
#include <math.h>

// ---------------- problem constants ----------------
#define N_USER   50000
#define N_MOVIE  20000
#define N_REVIEW 200000
#define NTOT     270000
#define NE       200000
#define HIDC     256
#define INC      768
#define OUTC     128

typedef __attribute__((ext_vector_type(8))) short short8;   // 8 bf16 (4 VGPRs)
typedef __attribute__((ext_vector_type(4))) float f32x4;    // MFMA accumulator

__device__ __forceinline__ float lrelu_f(float x){ return x > 0.f ? x : 0.01f*x; }

// order-preserving float<->uint encoding for atomicMax on floats (handles negatives)
__device__ __forceinline__ unsigned fenc(float f){
  unsigned u = __float_as_uint(f);
  return (u & 0x80000000u) ? ~u : (u | 0x80000000u);
}
__device__ __forceinline__ float fdec(unsigned e){
  return (e & 0x80000000u) ? __uint_as_float(e & 0x7FFFFFFFu) : __uint_as_float(~e);
}

// split two fp32 into packed bf16 hi pair and bf16 lo pair (round-half-up)
// hp = [bf16hi(f0), bf16hi(f1)] packed LE; lp = [bf16(f0-hi0), bf16(f1-hi1)]
__device__ __forceinline__ void split2(float f0, float f1, unsigned &hp, unsigned &lp){
  unsigned u0 = __float_as_uint(f0), u1 = __float_as_uint(f1);
  unsigned h0 = (u0 + 0x8000u) & 0xFFFF0000u;
  unsigned h1 = (u1 + 0x8000u) & 0xFFFF0000u;
  float l0 = f0 - __uint_as_float(h0);
  float l1 = f1 - __uint_as_float(h1);
  hp = (h0 >> 16) | h1;
  lp = ((__float_as_uint(l0) + 0x8000u) >> 16) | ((__float_as_uint(l1) + 0x8000u) & 0xFFFF0000u);
}

// ---------------- effective-weight prep ----------------
__global__ void prep_weights(const float* __restrict__ Wk, const float* __restrict__ bk,
                             const float* __restrict__ Wv, const float* __restrict__ bv,
                             const float* __restrict__ a_rel, const float* __restrict__ m_rel,
                             const float* __restrict__ p_rel,
                             float* __restrict__ WkE, float* __restrict__ bkE,
                             float* __restrict__ WvE, float* __restrict__ bvE)
{
  int bid = blockIdx.x;
  int kv  = bid / (2*3*257);          // 0 = key path, 1 = value path
  int rem = bid % (2*3*257);
  int ls  = rem / 257;
  int i   = rem % 257;                // 256 == bias row
  int l = ls / 3, s = ls % 3;
  const int es_map[3] = {1, 0, 2};
  int e = es_map[s];
  int j = threadIdx.x;                // output column 0..255
  int h = j >> 5, eo = j & 31;

  const float* rel = (kv == 0 ? a_rel : m_rel) + (size_t)((l*3+e)*8 + h)*1024 + eo; // [d*32]
  float scale = 1.f;
  if (kv == 0) scale = p_rel[(l*3+e)*8 + h] * 0.17677669529663687f; // 1/sqrt(32)

  float acc = 0.f;
  if (i < 256) {
    const float* wrow = (kv == 0 ? Wk : Wv) + ((size_t)(l*3+s)*256 + i)*256 + h*32;
    #pragma unroll
    for (int d = 0; d < 32; ++d) acc += wrow[d] * rel[d*32];
    acc *= scale;
    (kv == 0 ? WkE : WvE)[((size_t)(l*3+s)*256 + i)*256 + j] = acc;
  } else {
    const float* brow = (kv == 0 ? bk : bv) + (size_t)(l*3+s)*256 + h*32;
    #pragma unroll
    for (int d = 0; d < 32; ++d) acc += brow[d] * rel[d*32];
    acc *= scale;
    (kv == 0 ? bkE : bvE)[(size_t)(l*3+s)*256 + j] = acc;
  }
}

// ---------------- bf16x3 split-precision MFMA GEMM ----------------
// C = epilogue(A@B + bias).  A [M,K] f32 rm, B [K,N] f32 rm, C [M,N] f32 rm.
// mode 0: leaky_relu; 1: none; 2: g*(acc+bias)+(1-g)*skipbuf, g=sigmoid(*skipscalar)
// Tile: 128x128, BK=32, 4 waves (each 64x64 = 4x4 fragments of 16x16x32 MFMA).
// A,B split on the fly into bf16 hi/lo; products AhBh+AhBl+AlBh accumulated in fp32.
// LDS layout: Ah/Al [row][k] bf16 (row stride 32), Bh/Bl transposed [col][k];
// 16B slots XOR-swizzled by ((row>>1)&3) for conflict-free ds_read_b128/writes.
#define LOAD_TILES(KOFF) do {                                                        \
    _Pragma("unroll")                                                                \
    for (int q = 0; q < 4; ++q) {                                                    \
      int gr = bm + rA0 + q*32;                                                      \
      a4[q] = (gr < M) ? *(const float4*)(A + (size_t)gr*K + (KOFF) + ch*4)          \
                       : make_float4(0.f,0.f,0.f,0.f);                               \
    }                                                                                \
    _Pragma("unroll")                                                                \
    for (int kk = 0; kk < 16; ++kk)                                                  \
      bb[kk] = B[(size_t)((KOFF) + khB*16 + kk)*N + bn + cB];                        \
  } while(0)

__global__ __launch_bounds__(256, 2) void gemm_bf16x3(
    const float* __restrict__ A, const float* __restrict__ B,
    const float* __restrict__ bias, float* __restrict__ C,
    int M, int N, int K, int mode,
    const float* __restrict__ skipbuf, const float* __restrict__ skipscalar)
{
  __shared__ unsigned short Ah[128*32], Al[128*32];   // 8 KiB each
  __shared__ unsigned short Bh[128*32], Bl[128*32];   // [col][k], transposed

  const int tid = threadIdx.x;
  const int bm = blockIdx.y * 128, bn = blockIdx.x * 128;

  const int lane = tid & 63, w = tid >> 6;
  const int wm = (w & 1) * 64, wn = (w >> 1) * 64;
  const int lr = lane & 15, lq = lane >> 4;

  // staging indices: A tile 128x32 f32 (8 float4 per row), B tile 32x128 f32
  const int rA0 = tid >> 3;          // local row 0..31 (+q*32)
  const int ch  = tid & 7;           // float4 chunk within row
  const int cB  = tid & 127;         // B column
  const int khB = tid >> 7;          // B k-half (0..1)

  float4 a4[4];
  float  bb[16];
  f32x4  acc[4][4] = {};

  LOAD_TILES(0);

  for (int k0 = 0; k0 < K; k0 += 32) {
    if (k0) __syncthreads();                  // prev iteration's frag reads done

    // ---- convert + write A (hi/lo) ----
    #pragma unroll
    for (int q = 0; q < 4; ++q) {
      int r  = rA0 + q*32;
      int sA = (ch >> 1) ^ ((r >> 1) & 3);
      int ia = r*32 + sA*8 + (ch & 1)*4;      // ushort units
      unsigned hp0, lp0, hp1, lp1;
      split2(a4[q].x, a4[q].y, hp0, lp0);
      split2(a4[q].z, a4[q].w, hp1, lp1);
      *(uint2*)&Ah[ia] = make_uint2(hp0, hp1);
      *(uint2*)&Al[ia] = make_uint2(lp0, lp1);
    }
    // ---- convert + write B transposed (hi/lo) ----
    {
      unsigned hp[8], lp[8];
      #pragma unroll
      for (int p = 0; p < 8; ++p) split2(bb[2*p], bb[2*p+1], hp[p], lp[p]);
      int s0 = (khB*2)     ^ ((cB >> 1) & 3);
      int s1 = (khB*2 + 1) ^ ((cB >> 1) & 3);
      *(uint4*)&Bh[cB*32 + s0*8] = make_uint4(hp[0],hp[1],hp[2],hp[3]);
      *(uint4*)&Bh[cB*32 + s1*8] = make_uint4(hp[4],hp[5],hp[6],hp[7]);
      *(uint4*)&Bl[cB*32 + s0*8] = make_uint4(lp[0],lp[1],lp[2],lp[3]);
      *(uint4*)&Bl[cB*32 + s1*8] = make_uint4(lp[4],lp[5],lp[6],lp[7]);
    }
    __syncthreads();

    if (k0 + 32 < K) { LOAD_TILES(k0 + 32); } // prefetch next tile; hides under MFMAs

    // ---- fragments + MFMA ----
    short8 ahf[4], alf[4];
    #pragma unroll
    for (int mi = 0; mi < 4; ++mi) {
      int r = wm + mi*16 + lr;
      int s = lq ^ ((r >> 1) & 3);
      ahf[mi] = *(const short8*)&Ah[r*32 + s*8];
      alf[mi] = *(const short8*)&Al[r*32 + s*8];
    }
    #pragma unroll
    for (int ni = 0; ni < 4; ++ni) {
      int c = wn + ni*16 + lr;
      int s = lq ^ ((c >> 1) & 3);
      short8 bhf = *(const short8*)&Bh[c*32 + s*8];
      short8 blf = *(const short8*)&Bl[c*32 + s*8];
      #pragma unroll
      for (int mi = 0; mi < 4; ++mi) {
        acc[mi][ni] = __builtin_amdgcn_mfma_f32_16x16x32_bf16(ahf[mi], bhf, acc[mi][ni], 0, 0, 0);
        acc[mi][ni] = __builtin_amdgcn_mfma_f32_16x16x32_bf16(ahf[mi], blf, acc[mi][ni], 0, 0, 0);
        acc[mi][ni] = __builtin_amdgcn_mfma_f32_16x16x32_bf16(alf[mi], bhf, acc[mi][ni], 0, 0, 0);
      }
    }
  }

  // ---- epilogue.  C/D layout: col = lane&15, row = (lane>>4)*4 + reg  [HW-verified]
  float g = 0.f;
  if (mode == 2) g = 1.f / (1.f + expf(-skipscalar[0]));
  #pragma unroll
  for (int mi = 0; mi < 4; ++mi) {
    #pragma unroll
    for (int j = 0; j < 4; ++j) {
      int row = bm + wm + mi*16 + lq*4 + j;
      if (row < M) {
        #pragma unroll
        for (int ni = 0; ni < 4; ++ni) {
          int col = bn + wn + ni*16 + lr;
          float v = acc[mi][ni][j] + bias[col];
          if (mode == 0) v = lrelu_f(v);
          else if (mode == 2) v = g * v + (1.f - g) * skipbuf[(size_t)row * N + col];
          C[(size_t)row * N + col] = v;
        }
      }
    }
  }
}

// ---------------- edge attention kernels ----------------
__global__ void init_attn(unsigned* __restrict__ maxb, float* __restrict__ denb, int n)
{
  int i = blockIdx.x * blockDim.x + threadIdx.x;
  if (i < n) { maxb[i] = fenc(-INFINITY); denb[i] = 0.f; }
}

__global__ void edge_logits(const float* __restrict__ Kb, const float* __restrict__ Qb,
                            const int* __restrict__ src, const int* __restrict__ dst,
                            float* __restrict__ lg, unsigned* __restrict__ maxb, int E)
{
  int idx = blockIdx.x * blockDim.x + threadIdx.x;
  if (idx >= E * 8) return;
  int e = idx >> 3, h = idx & 7;
  int r = src[e], c = dst[e];
  const float4* kp = (const float4*)(Kb + (size_t)r * 256 + h * 32);
  const float4* qp = (const float4*)(Qb + (size_t)c * 256 + h * 32);
  float s = 0.f;
  #pragma unroll
  for (int q = 0; q < 8; ++q) {
    float4 a = kp[q], b = qp[q];
    s += a.x*b.x + a.y*b.y + a.z*b.z + a.w*b.w;
  }
  lg[idx] = s;
  atomicMax(maxb + (size_t)c * 8 + h, fenc(s));
}

__global__ void edge_exp(const int* __restrict__ dst, float* __restrict__ lg,
                         const unsigned* __restrict__ maxb, float* __restrict__ denb, int E)
{
  int idx = blockIdx.x * blockDim.x + threadIdx.x;
  if (idx >= E * 8) return;
  int e = idx >> 3, h = idx & 7;
  int c = dst[e];
  float m = fdec(maxb[(size_t)c * 8 + h]);
  float ex = expf(lg[idx] - m);
  lg[idx] = ex;
  atomicAdd(denb + (size_t)c * 8 + h, ex);
}

__global__ void edge_scatter(const float* __restrict__ Vb, const int* __restrict__ src,
                             const int* __restrict__ dst, const float* __restrict__ lg,
                             const float* __restrict__ denb, float* outs, int E)
{
  int idx = blockIdx.x * blockDim.x + threadIdx.x;
  if (idx >= E * 64) return;
  int e = idx >> 6, r5 = idx & 63;
  int h = r5 >> 3, dq = r5 & 7;
  int r = src[e], c = dst[e];
  float w = lg[(size_t)e * 8 + h] / (denb[(size_t)c * 8 + h] + 1e-16f);
  float4 v = *(const float4*)(Vb + (size_t)r * 256 + h * 32 + dq * 4);
  float* o = outs + (size_t)c * 256 + h * 32 + dq * 4;
  atomicAdd(o + 0, v.x * w);
  atomicAdd(o + 1, v.y * w);
  atomicAdd(o + 2, v.z * w);
  atomicAdd(o + 3, v.w * w);
}

__global__ void gelu_inplace4(float4* x, size_t n4)
{
  size_t i = (size_t)blockIdx.x * blockDim.x + threadIdx.x;
  if (i >= n4) return;
  float4 v = x[i];
  v.x = 0.5f * v.x * (1.f + erff(v.x * 0.70710678118654752f));
  v.y = 0.5f * v.y * (1.f + erff(v.y * 0.70710678118654752f));
  v.z = 0.5f * v.z * (1.f + erff(v.z * 0.70710678118654752f));
  v.w = 0.5f * v.w * (1.f + erff(v.w * 0.70710678118654752f));
  x[i] = v;
}

// ---------------- launch ----------------
extern "C" void kernel_launch(void* const* d_in, const int* in_sizes, int n_in,
                              void* d_out, int out_size, void* d_ws, size_t ws_size,
                              hipStream_t stream)
{
  const float* xin[3] = { (const float*)d_in[0], (const float*)d_in[1], (const float*)d_in[2] };
  const int* src_e[3] = { (const int*)d_in[3], (const int*)d_in[5], (const int*)d_in[7] };
  const int* dst_e[3] = { (const int*)d_in[4], (const int*)d_in[6], (const int*)d_in[8] };
  const float* W1 = (const float*)d_in[9];   const float* b1 = (const float*)d_in[10];
  const float* W2 = (const float*)d_in[11];  const float* b2 = (const float*)d_in[12];
  const float* Wk = (const float*)d_in[13];  const float* bk = (const float*)d_in[14];
  const float* Wq = (const float*)d_in[15];  const float* bq = (const float*)d_in[16];
  const float* Wv = (const float*)d_in[17];  const float* bv = (const float*)d_in[18];
  const float* Wa = (const float*)d_in[19];  const float* ba = (const float*)d_in[20];
  const float* skip = (const float*)d_in[21];
  const float* a_rel = (const float*)d_in[22];
  const float* m_rel = (const float*)d_in[23];
  const float* p_rel = (const float*)d_in[24];
  float* out = (float*)d_out;

  const int Ns[3]  = { N_USER, N_MOVIE, N_REVIEW };
  const int off[3] = { 0, N_USER, N_USER + N_MOVIE };
  // edge types: (src_type, dst_type)
  const int es[3] = { 1, 0, 2 };
  const int et[3] = { 2, 2, 0 };

  float* ws = (float*)d_ws;
  const size_t NF = (size_t)NTOT * HIDC;     // 69.12M floats
  float* X    = ws;            ws += NF;
  float* Kb   = ws;            ws += NF;
  float* Qb   = ws;            ws += NF;
  float* Vb   = ws;            ws += NF;
  float* Outs = ws;            ws += NF;
  float* WkE  = ws;            ws += (size_t)2*3*256*256;
  float* WvE  = ws;            ws += (size_t)2*3*256*256;
  float* bkE  = ws;            ws += (size_t)2*3*256;
  float* bvE  = ws;            ws += (size_t)2*3*256;
  float* LG   = ws;            ws += (size_t)NE*8;
  unsigned* MAXB = (unsigned*)ws; ws += (size_t)N_REVIEW*8;
  float* DENB = ws;            ws += (size_t)N_REVIEW*8;

  // 1) effective K/V weights (fold a_rel/m_rel/p_rel into projections)
  prep_weights<<<2*3*257*2, 256, 0, stream>>>(Wk, bk, Wv, bv, a_rel, m_rel, p_rel,
                                              WkE, bkE, WvE, bvE);

  // 2) input MLP: X = lrelu(x @ W1 + b1)
  for (int t = 0; t < 3; ++t) {
    dim3 grid(HIDC/128, (Ns[t]+127)/128);
    gemm_bf16x3<<<grid, 256, 0, stream>>>(xin[t], W1, b1, X + (size_t)off[t]*HIDC,
                                          Ns[t], HIDC, INC, 0, nullptr, nullptr);
  }

  // 3) HGT layers
  for (int l = 0; l < 2; ++l) {
    for (int t = 0; t < 3; ++t) {
      dim3 grid(HIDC/128, (Ns[t]+127)/128);
      size_t wo = (size_t)(l*3+t)*256*256, bo = (size_t)(l*3+t)*256, xo = (size_t)off[t]*HIDC;
      gemm_bf16x3<<<grid, 256, 0, stream>>>(X + xo, WkE + wo, bkE + bo, Kb + xo,
                                            Ns[t], HIDC, HIDC, 1, nullptr, nullptr);
      gemm_bf16x3<<<grid, 256, 0, stream>>>(X + xo, Wq + wo, bq + bo, Qb + xo,
                                            Ns[t], HIDC, HIDC, 1, nullptr, nullptr);
      gemm_bf16x3<<<grid, 256, 0, stream>>>(X + xo, WvE + wo, bvE + bo, Vb + xo,
                                            Ns[t], HIDC, HIDC, 1, nullptr, nullptr);
    }
    hipMemsetAsync(Outs, 0, NF * sizeof(float), stream);
    for (int e = 0; e < 3; ++e) {
      int s = es[e], t = et[e];
      int nt8 = Ns[t] * 8;
      init_attn<<<(nt8+255)/256, 256, 0, stream>>>(MAXB, DENB, nt8);
      edge_logits<<<(NE*8+255)/256, 256, 0, stream>>>(Kb + (size_t)off[s]*HIDC,
                                                      Qb + (size_t)off[t]*HIDC,
                                                      src_e[e], dst_e[e], LG, MAXB, NE);
      edge_exp<<<(NE*8+255)/256, 256, 0, stream>>>(dst_e[e], LG, MAXB, DENB, NE);
      edge_scatter<<<(NE*64+255)/256, 256, 0, stream>>>(Vb + (size_t)off[s]*HIDC,
                                                        src_e[e], dst_e[e], LG, DENB,
                                                        Outs + (size_t)off[t]*HIDC, NE);
    }
    gelu_inplace4<<<(unsigned)((NF/4 + 255)/256), 256, 0, stream>>>((float4*)Outs, NF/4);
    for (int t = 0; t < 3; ++t) {
      dim3 grid(HIDC/128, (Ns[t]+127)/128);
      size_t wo = (size_t)(l*3+t)*256*256, bo = (size_t)(l*3+t)*256, xo = (size_t)off[t]*HIDC;
      gemm_bf16x3<<<grid, 256, 0, stream>>>(Outs + xo, Wa + wo, ba + bo, X + xo,
                                            Ns[t], HIDC, HIDC, 2, X + xo, skip + l*3 + t);
    }
  }

  // 4) output MLP: out = lrelu(X @ W2 + b2), concat [user, movie, review]
  for (int t = 0; t < 3; ++t) {
    dim3 grid(OUTC/128, (Ns[t]+127)/128);
    gemm_bf16x3<<<grid, 256, 0, stream>>>(X + (size_t)off[t]*HIDC, W2, b2,
                                          out + (size_t)off[t]*OUTC,
                                          Ns[t], OUTC, HIDC, 0, nullptr, nullptr);
  }
}